// Round 1
// baseline (78.815 us; speedup 1.0000x reference)
//
#include <hip/hip_runtime.h>
#include <hip/hip_bf16.h>

typedef __attribute__((ext_vector_type(8))) __bf16 bf16x8;
typedef __attribute__((ext_vector_type(4))) float f32x4;

static constexpr int BROWS = 65536;
static constexpr int SDIM  = 512;
static constexpr int CDIM  = 256;
static constexpr float SLOPE = 0.01f;
static constexpr float HLP = 0.9189385332046727f;  // 0.5*log(2*pi)

// ws bf16 layout: W1T [64][512], W2T [32][64], W3T [256][32]
static constexpr int W1T_OFF = 0;
static constexpr int W2T_OFF = 64 * 512;
static constexpr int W3T_OFF = 64 * 512 + 32 * 64;
static constexpr int WS_ELEMS = W3T_OFF + 256 * 32;   // 43008

__global__ __launch_bounds__(256) void prep_weights(
    const float* __restrict__ W1, const float* __restrict__ W2,
    const float* __restrict__ W3, __bf16* __restrict__ ws)
{
    int tid = blockIdx.x * 256 + threadIdx.x;
    if (tid < 64 * 512) {                       // W1 [512][64] -> W1T [64][512]
        int n = tid >> 9, k = tid & 511;
        ws[W1T_OFF + tid] = (__bf16)W1[k * 64 + n];
    } else if (tid < 64 * 512 + 32 * 64) {      // W2 [64][32] -> W2T [32][64]
        int t = tid - 64 * 512;
        int n = t >> 6, k = t & 63;
        ws[W2T_OFF + t] = (__bf16)W2[k * 32 + n];
    } else if (tid < WS_ELEMS) {                // W3 [32][256] -> W3T [256][32]
        int t = tid - (64 * 512 + 32 * 64);
        int n = t >> 5, k = t & 31;
        ws[W3T_OFF + t] = (__bf16)W3[k * 256 + n];
    }
}

// swizzled LDS element index: row stride 64 bf16 (128B), XOR row&7 into 16B-chunk bits
__device__ __forceinline__ int swz(int row, int elem) {
    return (row * 64 + elem) ^ ((row & 7) << 3);
}

__global__ __launch_bounds__(256, 4) void policy_fused(
    const float* __restrict__ state, const float* __restrict__ b1,
    const float* __restrict__ b2, const float* __restrict__ b3,
    const float* __restrict__ noise, const __bf16* __restrict__ ws,
    float* __restrict__ actions, float* __restrict__ logp)
{
    __shared__ __align__(16) __bf16 h1s[64 * 64];
    __shared__ __align__(16) __bf16 h2s[64 * 64];   // cols 0..31 used

    const int tid  = threadIdx.x;
    const int wave = tid >> 6;
    const int lane = tid & 63;
    const int lr   = lane & 15;   // A-row / B-col / C-col index
    const int lq   = lane >> 4;   // k-chunk / C-row-quad index

    const int rowbase = blockIdx.x * 64 + wave * 16;   // this wave's 16 rows

    const __bf16* W1T = ws + W1T_OFF;
    const __bf16* W2T = ws + W2T_OFF;
    const __bf16* W3T = ws + W3T_OFF;

    const f32x4 zero4 = {0.f, 0.f, 0.f, 0.f};

    // ---------------- layer 1: [16 rows] x [64 cols], K=512 ----------------
    f32x4 acc[4] = {zero4, zero4, zero4, zero4};
    const float* sp = state + (size_t)(rowbase + lr) * SDIM + lq * 8;
    #pragma unroll 4
    for (int k0 = 0; k0 < SDIM; k0 += 32) {
        float4 sa = *(const float4*)(sp + k0);
        float4 sb = *(const float4*)(sp + k0 + 4);
        bf16x8 a = {(__bf16)sa.x, (__bf16)sa.y, (__bf16)sa.z, (__bf16)sa.w,
                    (__bf16)sb.x, (__bf16)sb.y, (__bf16)sb.z, (__bf16)sb.w};
        const __bf16* wp = W1T + lr * SDIM + k0 + lq * 8;
        #pragma unroll
        for (int n = 0; n < 4; ++n) {
            bf16x8 b = *(const bf16x8*)(wp + n * 16 * SDIM);
            acc[n] = __builtin_amdgcn_mfma_f32_16x16x32_bf16(a, b, acc[n], 0, 0, 0);
        }
    }
    #pragma unroll
    for (int n = 0; n < 4; ++n) {
        float bv = b1[n * 16 + lr];
        #pragma unroll
        for (int r = 0; r < 4; ++r) {
            float v = acc[n][r] + bv;
            v = (v >= 0.f) ? v : SLOPE * v;
            int row = wave * 16 + lq * 4 + r;
            h1s[swz(row, n * 16 + lr)] = (__bf16)v;
        }
    }
    __syncthreads();

    // ---------------- layer 2: [16 rows] x [32 cols], K=64 ----------------
    f32x4 c2[2] = {zero4, zero4};
    #pragma unroll
    for (int kk = 0; kk < 2; ++kk) {
        bf16x8 a = *(const bf16x8*)&h1s[swz(wave * 16 + lr, kk * 32 + lq * 8)];
        const __bf16* wp = W2T + lr * 64 + kk * 32 + lq * 8;
        #pragma unroll
        for (int n = 0; n < 2; ++n) {
            bf16x8 b = *(const bf16x8*)(wp + n * 16 * 64);
            c2[n] = __builtin_amdgcn_mfma_f32_16x16x32_bf16(a, b, c2[n], 0, 0, 0);
        }
    }
    #pragma unroll
    for (int n = 0; n < 2; ++n) {
        float bv = b2[n * 16 + lr];
        #pragma unroll
        for (int r = 0; r < 4; ++r) {
            float v = c2[n][r] + bv;
            v = (v >= 0.f) ? v : SLOPE * v;
            int row = wave * 16 + lq * 4 + r;
            h2s[swz(row, n * 16 + lr)] = (__bf16)v;
        }
    }
    __syncthreads();

    // ---------------- layer 3 + epilogue: [16 rows] x [256 cols], K=32 ----------------
    bf16x8 a3 = *(const bf16x8*)&h2s[swz(wave * 16 + lr, lq * 8)];
    float lp0 = 0.f, lp1 = 0.f, lp2 = 0.f, lp3 = 0.f;
    const int grow0 = rowbase + lq * 4;   // rows grow0 .. grow0+3 (this lane's C rows)
    #pragma unroll 4
    for (int n = 0; n < 16; ++n) {
        bf16x8 b = *(const bf16x8*)(W3T + (n * 16 + lr) * 32 + lq * 8);
        f32x4 c = __builtin_amdgcn_mfma_f32_16x16x32_bf16(a3, b, zero4, 0, 0, 0);
        int col = n * 16 + lr;
        float bv = b3[col];
        #pragma unroll
        for (int r = 0; r < 4; ++r) {
            size_t idx = (size_t)(grow0 + r) * CDIM + col;
            float mean = c[r] + bv;
            float av = mean + noise[idx];
            actions[idx] = av;
            float z = av - mean;            // replicate reference rounding exactly
            float t = -0.5f * z * z - HLP;
            if      (r == 0) lp0 += t;
            else if (r == 1) lp1 += t;
            else if (r == 2) lp2 += t;
            else             lp3 += t;
        }
    }
    // reduce over the 16 lanes (lr) sharing each row
    #pragma unroll
    for (int m = 1; m < 16; m <<= 1) {
        lp0 += __shfl_xor(lp0, m, 64);
        lp1 += __shfl_xor(lp1, m, 64);
        lp2 += __shfl_xor(lp2, m, 64);
        lp3 += __shfl_xor(lp3, m, 64);
    }
    if      (lr == 0) logp[grow0 + 0] = lp0;
    else if (lr == 1) logp[grow0 + 1] = lp1;
    else if (lr == 2) logp[grow0 + 2] = lp2;
    else if (lr == 3) logp[grow0 + 3] = lp3;
}

extern "C" void kernel_launch(void* const* d_in, const int* in_sizes, int n_in,
                              void* d_out, int out_size, void* d_ws, size_t ws_size,
                              hipStream_t stream)
{
    const float* state = (const float*)d_in[0];
    const float* W1    = (const float*)d_in[1];
    const float* b1    = (const float*)d_in[2];
    const float* W2    = (const float*)d_in[3];
    const float* b2    = (const float*)d_in[4];
    const float* W3    = (const float*)d_in[5];
    const float* b3    = (const float*)d_in[6];
    const float* noise = (const float*)d_in[7];

    if (ws_size < (size_t)WS_ELEMS * sizeof(__bf16)) return;  // need 86 KB scratch
    __bf16* ws = (__bf16*)d_ws;

    float* actions = (float*)d_out;
    float* logp    = actions + (size_t)BROWS * CDIM;

    prep_weights<<<(WS_ELEMS + 255) / 256, 256, 0, stream>>>(W1, W2, W3, ws);
    policy_fused<<<BROWS / 64, 256, 0, stream>>>(state, b1, b2, b3, noise, ws,
                                                 actions, logp);
}